// Round 5
// baseline (165.708 us; speedup 1.0000x reference)
//
#include <hip/hip_runtime.h>
#include <math.h>

// Problem: b=2, h=8, n=1024, d=64, DIM=512. Inputs/outputs FLOAT32.
// Internal pipeline bf16 MFMA (f32 accumulate). SCALE = 1/8.
// R22 = R21 with the real R20/R21 bug fixed: the staged S_u GEMM's sig
// (B-operand) loads were missing the C0 column offset (gB + it*64 instead
// of gB + j0 = gB + C0 + it*64) -> wrong sig columns for all ct>0 tiles,
// deterministic absmax 3.2e-2 in both rounds. A-operand was correct; now
// both use j0, matching the verified R17 k_scores addressing.
// Flash fusion otherwise unchanged: k_scores+k_pv_soft -> k_flash (online
// softmax over S = S_c*SCALE - silu(term1 @ sig^T)) + k_comb combine.

typedef __bf16 bf16x8 __attribute__((ext_vector_type(8)));
typedef float f32x4 __attribute__((ext_vector_type(4)));

#define SCALE 0.125f

// async global->LDS: lane deposits 16B at (wave-uniform base + lane*16)
#define GLL(g, l) __builtin_amdgcn_global_load_lds(                         \
    (const __attribute__((address_space(1))) void*)(g),                     \
    (__attribute__((address_space(3))) void*)(l), 16, 0, 0)

__device__ __forceinline__ unsigned short f2bf(float f){
  unsigned int x = __builtin_bit_cast(unsigned int, f);
  unsigned int r = (x + 0x7fffu + ((x >> 16) & 1u)) >> 16;  // RNE
  return (unsigned short)r;
}
__device__ __forceinline__ float bf2f(unsigned short u){
  unsigned int x = ((unsigned int)u) << 16;
  return __builtin_bit_cast(float, x);
}
__device__ __forceinline__ f32x4 mfma16(bf16x8 a, bf16x8 b, f32x4 c){
  return __builtin_amdgcn_mfma_f32_16x16x32_bf16(a, b, c, 0, 0, 0);
}
__device__ __forceinline__ bf16x8 ld8(const unsigned short* p){
  return *(const bf16x8*)p;
}

// cumulative tile counts for 64-row-band lower-tri (k_qk map)
__device__ const unsigned char QK_CUM[16] =
  {0,1,2,4,6,9,12,16,20,25,30,36,42,49,56,64};   // total 72

// k_flash block map: (rb, g) pairs sorted by descending work (j-chunk count)
__device__ const unsigned char FL_RB[40] =
  {15,14,13,12,15,11,14,10,13, 9,12, 8,15,11, 7,14,10, 6,13, 9,
    5,12, 8, 4,15,11, 7, 3,14,10, 6, 2,13, 9, 5, 1,12, 8, 4, 0};
__device__ const unsigned char FL_G[40] =
  { 0, 0, 0, 0, 1, 0, 1, 0, 1, 0, 1, 0, 2, 1, 0, 2, 1, 0, 2, 1,
    0, 2, 1, 0, 3, 2, 1, 0, 3, 2, 1, 0, 3, 2, 1, 0, 3, 2, 1, 0};

// ---------------- K0: x f32->bf16 (blocks 0..575, stride) + w transpose -----
__global__ __launch_bounds__(256) void k_prep(
    const float* __restrict__ x,
    const float* __restrict__ w0, const float* __restrict__ w1,
    const float* __restrict__ w2, const float* __restrict__ w3,
    const float* __restrict__ w4, const float* __restrict__ w5,
    const float* __restrict__ w6,
    unsigned short* __restrict__ xb, unsigned short* __restrict__ wT){
  int t = threadIdx.x;
  if (blockIdx.x < 576){
    for (int i = blockIdx.x * 256 + t; i < 262144; i += 576 * 256){
      float4 v = ((const float4*)x)[i];
      ushort4 o; o.x = f2bf(v.x); o.y = f2bf(v.y); o.z = f2bf(v.z); o.w = f2bf(v.w);
      ((ushort4*)xb)[i] = o;
    }
    return;
  }
  __shared__ float lds[64 * 65];
  int bx = blockIdx.x - 576;                    // 448 = 7 mats * 64 tiles
  int mat = bx >> 6, tile = bx & 63, tr = tile >> 3, tc = tile & 7;
  int k0 = tr * 64, c0 = tc * 64;
  const float* src;
  switch (mat){
    case 0: src = w0; break; case 1: src = w1; break; case 2: src = w2; break;
    case 3: src = w3; break; case 4: src = w4; break; case 5: src = w5; break;
    default: src = w6; break;
  }
#pragma unroll
  for (int i = 0; i < 4; ++i){
    int r = (t >> 4) + i * 16, c4 = (t & 15) * 4;
    float4 v = *(const float4*)(src + (size_t)(k0 + r) * 512 + c0 + c4);
    lds[r * 65 + c4 + 0] = v.x; lds[r * 65 + c4 + 1] = v.y;
    lds[r * 65 + c4 + 2] = v.z; lds[r * 65 + c4 + 3] = v.w;
  }
  __syncthreads();
  unsigned short* dst = wT + (size_t)mat * 262144;
#pragma unroll
  for (int i = 0; i < 4; ++i){
    int oc = (t >> 4) + i * 16;
    int kq = (t & 15) * 4;
    ushort4 o;
    o.x = f2bf(lds[(kq + 0) * 65 + oc]);
    o.y = f2bf(lds[(kq + 1) * 65 + oc]);
    o.z = f2bf(lds[(kq + 2) * 65 + oc]);
    o.w = f2bf(lds[(kq + 3) * 65 + oc]);
    *(ushort4*)(dst + (size_t)(c0 + oc) * 512 + k0 + kq) = o;
  }
}

// ---------------- K1: fused projections, 64x128 tiles, 768 blocks -----------
__global__ __launch_bounds__(256) void k_proj(
    const unsigned short* __restrict__ xb, const unsigned short* __restrict__ wT,
    unsigned short* __restrict__ P){
  __shared__ __align__(16) unsigned short sA[2 * 2 * 64 * 32];   // [buf][half]
  __shared__ __align__(16) unsigned short sB[2 * 2 * 128 * 32];
  int t = threadIdx.x, lane = t & 63, l16 = lane & 15, quad = lane >> 4;
  int w = t >> 6, wm = w >> 1, wn = w & 1;
  int bx = blockIdx.x;                       // 768 = 32 Mtiles * 24 Ntiles
  int mt = bx / 24, nt = bx - mt * 24;
  int M0 = mt * 64, N0 = nt * 128;
  int matb = N0 >> 9;
  int nin = N0 & 511;
  int srow = (lane >> 2), scol = (lane & 3) * 8;
  const unsigned short* gA = xb + (size_t)(M0 + w*16 + srow) * 512 + scol;
  const unsigned short* gB = wT + (size_t)matb * 262144
                               + (size_t)(nin + w*32 + srow) * 512 + scol;
  unsigned short* lA = sA + (w*16) * 32;
  unsigned short* lB = sB + (w*32) * 32;
  f32x4 acc[4][2] = {};
#define STAGE_PROJ(buf, k0) do {                                   \
    GLL(gA + (k0),               lA + (buf)*4096);                 \
    GLL(gB + (k0),               lB + (buf)*8192);                 \
    GLL(gB + (k0) + 16*512,      lB + (buf)*8192 + 16*32);         \
    GLL(gA + (k0) + 32,          lA + (buf)*4096 + 2048);          \
    GLL(gB + (k0) + 32,          lB + (buf)*8192 + 4096);          \
    GLL(gB + (k0) + 32 + 16*512, lB + (buf)*8192 + 4096 + 16*32);  \
  } while(0)
  STAGE_PROJ(0, 0);
  for (int it = 0; it < 8; ++it){
    if (it < 7){
      STAGE_PROJ((it+1) & 1, (it+1)*64);
      asm volatile("s_waitcnt vmcnt(6)" ::: "memory");
    } else {
      asm volatile("s_waitcnt vmcnt(0)" ::: "memory");
    }
    __builtin_amdgcn_s_barrier();
    int b = it & 1;
#pragma unroll
    for (int h = 0; h < 2; ++h){
      bf16x8 aw[4], ax[2];
#pragma unroll
      for (int fi = 0; fi < 4; ++fi)
        aw[fi] = *(const bf16x8*)(sB + b*8192 + h*4096 + (wn*64 + fi*16 + l16) * 32 + quad * 8);
#pragma unroll
      for (int mi = 0; mi < 2; ++mi)
        ax[mi] = *(const bf16x8*)(sA + b*4096 + h*2048 + (wm*32 + mi*16 + l16) * 32 + quad * 8);
#pragma unroll
      for (int fi = 0; fi < 4; ++fi)
#pragma unroll
        for (int mi = 0; mi < 2; ++mi)
          acc[fi][mi] = mfma16(aw[fi], ax[mi], acc[fi][mi]);
    }
    __builtin_amdgcn_s_barrier();
  }
#undef STAGE_PROJ
#pragma unroll
  for (int fi = 0; fi < 4; ++fi)
#pragma unroll
    for (int mi = 0; mi < 2; ++mi){
      int row = M0 + wm*32 + mi*16 + l16;
      int b_ = row >> 10, n_ = row & 1023;
      int c0 = N0 + wn*64 + fi*16 + quad*4;
      int h = (c0 & 511) >> 6, d = c0 & 63;
      int bh = b_*8 + h;
      ushort4 o;
      o.x = f2bf(acc[fi][mi][0]); o.y = f2bf(acc[fi][mi][1]);
      o.z = f2bf(acc[fi][mi][2]); o.w = f2bf(acc[fi][mi][3]);
      *(ushort4*)(P + (size_t)(matb*16 + bh) * 65536 + (size_t)n_ * 64 + d) = o;
    }
}

// ---------------- K2: vct (blocks 0..255) + qk as 64x128, ONE barrier -------
__global__ __launch_bounds__(256) void k_qk_vct(
    const unsigned short* __restrict__ P,
    unsigned short* __restrict__ term1, unsigned short* __restrict__ sig,
    unsigned short* __restrict__ vcT){
  int t = threadIdx.x;
  if (blockIdx.x < 256){
    __shared__ unsigned short lds[64 * 72];
    int bh = blockIdx.x >> 4, nt = blockIdx.x & 15;
    int N0 = nt * 64;
    const unsigned short* src = P + (size_t)(5*16 + bh) * 65536 + (size_t)N0 * 64;
#pragma unroll
    for (int i2 = 0; i2 < 2; ++i2){
      int id = i2 * 256 + t;
      int r = id >> 3, c8 = (id & 7) * 8;
      ushort4 v0 = *(const ushort4*)(src + r * 64 + c8);
      ushort4 v1 = *(const ushort4*)(src + r * 64 + c8 + 4);
      *(ushort4*)(lds + r * 72 + c8) = v0;
      *(ushort4*)(lds + r * 72 + c8 + 4) = v1;
    }
    __syncthreads();
    unsigned short* dst = vcT + (size_t)bh * 65536;
#pragma unroll
    for (int i2 = 0; i2 < 2; ++i2){
      int id = i2 * 256 + t;
      int dd = id >> 3, n8 = (id & 7) * 8;
      ushort4 a, b;
      a.x = lds[(n8+0)*72 + dd]; a.y = lds[(n8+1)*72 + dd];
      a.z = lds[(n8+2)*72 + dd]; a.w = lds[(n8+3)*72 + dd];
      b.x = lds[(n8+4)*72 + dd]; b.y = lds[(n8+5)*72 + dd];
      b.z = lds[(n8+6)*72 + dd]; b.w = lds[(n8+7)*72 + dd];
      *(ushort4*)(dst + (size_t)dd * 1024 + N0 + n8) = a;
      *(ushort4*)(dst + (size_t)dd * 1024 + N0 + n8 + 4) = b;
    }
    return;
  }
  __shared__ unsigned short sA[2 * 64 * 32], sB[2 * 128 * 32];
  int id = blockIdx.x - 256;
  int bh = id & 15, tt = id >> 4;              // tt in [0,144)
  int mat = (tt >= 72);                        // 0=term1, 1=sig
  int tl = mat ? tt - 72 : tt;                 // [0,72)
  int rb = 15;
  while (QK_CUM[rb] > tl) --rb;
  int ct = tl - QK_CUM[rb];                    // ct <= rb>>1
  int R0, C0;
  const unsigned short *Asrc, *Bsrc;
  if (!mat){ R0 = rb * 64;        C0 = ct * 128;        // term1 rows=i, cols=j
             Asrc = P + (size_t)(3*16 + bh) * 65536;    // q_c
             Bsrc = P + (size_t)(2*16 + bh) * 65536; }  // v_u
  else     { R0 = (15 - rb) * 64; C0 = (7 - ct) * 128;  // sig rows=k, cols=j
             Asrc = P + (size_t)(0*16 + bh) * 65536;    // q_u
             Bsrc = P + (size_t)(1*16 + bh) * 65536; }  // k_u
  int lane = t & 63, l16 = lane & 15, quad = lane >> 4;
  int w = t >> 6, wm = w >> 1, wn = w & 1;
  int srow = lane >> 2, scol = (lane & 3) * 8;
  const unsigned short* gA = Asrc + (size_t)(R0 + w*16 + srow) * 64 + scol;
  const unsigned short* gB = Bsrc + (size_t)(C0 + w*32 + srow) * 64 + scol;
  unsigned short* lA0 = sA + (w*16) * 32;
  unsigned short* lB0 = sB + (w*32) * 32;
  unsigned short* lA1 = lA0 + 64 * 32;
  unsigned short* lB1 = lB0 + 128 * 32;
  f32x4 acc[4][2] = {};
  GLL(gA,              lA0);
  GLL(gB,              lB0);
  GLL(gB + 16*64,      lB0 + 16*32);
  GLL(gA + 32,         lA1);
  GLL(gB + 32,         lB1);
  GLL(gB + 32 + 16*64, lB1 + 16*32);
  __syncthreads();
#pragma unroll
  for (int h = 0; h < 2; ++h){
    bf16x8 af[2], bfr[4];
#pragma unroll
    for (int mi = 0; mi < 2; ++mi)
      af[mi] = *(const bf16x8*)(sA + h*2048 + (wm*32 + mi*16 + l16) * 32 + quad * 8);
#pragma unroll
    for (int fi = 0; fi < 4; ++fi)
      bfr[fi] = *(const bf16x8*)(sB + h*4096 + (wn*64 + fi*16 + l16) * 32 + quad * 8);
#pragma unroll
    for (int fi = 0; fi < 4; ++fi)
#pragma unroll
      for (int mi = 0; mi < 2; ++mi)
        acc[fi][mi] = mfma16(bfr[fi], af[mi], acc[fi][mi]);
  }
  unsigned short* out = (mat ? sig : term1) + (size_t)bh * 1048576;
#pragma unroll
  for (int fi = 0; fi < 4; ++fi)
#pragma unroll
    for (int mi = 0; mi < 2; ++mi){
      int row = R0 + wm*32 + mi*16 + l16;
      int c0 = C0 + wn*64 + fi*16 + quad*4;
      ushort4 o;
#pragma unroll
      for (int r = 0; r < 4; ++r){
        int col = c0 + r;
        float v = acc[fi][mi][r] * SCALE;
        unsigned short res;
        if (!mat) res = (col <= row) ? f2bf(v) : (unsigned short)0;
        else      res = (col >  row) ? f2bf(1.f / (1.f + expf(-v))) : (unsigned short)0;
        ((unsigned short*)&o)[r] = res;
      }
      *(ushort4*)(out + (size_t)row * 1024 + c0) = o;
    }
}

// ---------------- K3: flash-fused scores + online softmax + PV --------------
// 640 blocks = 16 bh x 40 (rb,g) splits (heaviest-first). Per k-tile (128
// cols): S_u staged GEMM over j (A and B both at column j0 = C0 + it*64),
// S_c register GEMM, mask, online softmax (m/s state in LDS), probs bf16 ->
// LDS[64][136], PV MFMA vs vcT into register O. G==1 bands (rb<=3) write O2
// directly; else f32 partials + (m,s).
__global__ __launch_bounds__(256) void k_flash(
    const unsigned short* __restrict__ P,
    const unsigned short* __restrict__ term1,
    const unsigned short* __restrict__ sig,
    const unsigned short* __restrict__ vcT,
    float* __restrict__ Opart, float* __restrict__ MS,
    unsigned short* __restrict__ O2){
  __shared__ __align__(16) unsigned short sA[2 * 64 * 32];   // [half][64][32]
  __shared__ __align__(16) unsigned short sB[2 * 128 * 32];
  __shared__ __align__(16) unsigned short probs[64 * 136];
  __shared__ float wpm[2][64], wps[2][64];
  __shared__ float alpha_s[64], mrun_s[64], srun_s[64];
  int t = threadIdx.x;
  int bh = blockIdx.x & 15, q = blockIdx.x >> 4;
  int rb = FL_RB[q], g = FL_G[q];
  int T = (rb >> 1) + 1, G = (T + 1) >> 1;
  int ct0 = 2 * g, ctN = min(ct0 + 2, T);
  int R0 = rb * 64;
  size_t sbase = (size_t)bh * 1048576;
  int lane = t & 63, l16 = lane & 15, quad = lane >> 4, w = t >> 6;
  int wm = w >> 1, wn = w & 1;
  int srow = lane >> 2, scol = (lane & 3) * 8;
  unsigned short* lA0 = sA + (w*16) * 32;
  unsigned short* lB0 = sB + (w*32) * 32;
  unsigned short* lA1 = lA0 + 2048;
  unsigned short* lB1 = lB0 + 4096;
  const unsigned short* Qc = P + (size_t)(3*16 + bh) * 65536;
  const unsigned short* Kc = P + (size_t)(4*16 + bh) * 65536;
  const unsigned short* Vt = vcT + (size_t)bh * 65536;
  if (t < 64){ mrun_s[t] = -INFINITY; srun_s[t] = 0.f; }
  // hoisted Qc fragments (rows fixed per block)
  bf16x8 aq[2][2];
#pragma unroll
  for (int mi = 0; mi < 2; ++mi)
#pragma unroll
    for (int kk = 0; kk < 2; ++kk)
      aq[mi][kk] = ld8(Qc + (size_t)(R0 + wm*32 + mi*16 + l16) * 64 + kk*32 + quad*8);
  f32x4 acc_o[4] = {};   // O[row=16w+quad*4+r][d=fi*16+l16]
  const unsigned short* gA = term1 + sbase + (size_t)(R0 + w*16 + srow) * 1024 + scol;
  const unsigned short* gBs = sig  + sbase;

  for (int ct = ct0; ct < ctN; ++ct){
    int C0 = ct * 128;
    int n_it = rb + 1 - 2*ct;           // 64-wide j-chunks, >= 1
    const unsigned short* gB = gBs + (size_t)(C0 + w*32 + srow) * 1024 + scol;
    f32x4 acc_u[4][2] = {};
    for (int it = 0; it < n_it; ++it){
      int j0 = C0 + it * 64;
      GLL(gA + j0,              lA0);
      GLL(gB + j0,              lB0);
      GLL(gB + j0 + 16*1024,    lB0 + 16*32);
      GLL(gA + j0 + 32,           lA1);
      GLL(gB + j0 + 32,           lB1);
      GLL(gB + j0 + 32 + 16*1024, lB1 + 16*32);
      __syncthreads();
#pragma unroll
      for (int h = 0; h < 2; ++h){
        bf16x8 af[2], bfr[4];
#pragma unroll
        for (int mi = 0; mi < 2; ++mi)
          af[mi] = *(const bf16x8*)(sA + h*2048 + (wm*32 + mi*16 + l16) * 32 + quad * 8);
#pragma unroll
        for (int fi = 0; fi < 4; ++fi)
          bfr[fi] = *(const bf16x8*)(sB + h*4096 + (wn*64 + fi*16 + l16) * 32 + quad * 8);
#pragma unroll
        for (int fi = 0; fi < 4; ++fi)
#pragma unroll
          for (int mi = 0; mi < 2; ++mi)
            acc_u[fi][mi] = mfma16(bfr[fi], af[mi], acc_u[fi][mi]);
      }
      __syncthreads();
    }
    // S_c = q_c @ k_c^T (K=64), register-direct
    f32x4 acc_c[4][2] = {};
#pragma unroll
    for (int kk = 0; kk < 2; ++kk){
      bf16x8 bfr[4];
#pragma unroll
      for (int fi = 0; fi < 4; ++fi)
        bfr[fi] = ld8(Kc + (size_t)(C0 + wn*64 + fi*16 + l16) * 64 + kk*32 + quad*8);
#pragma unroll
      for (int fi = 0; fi < 4; ++fi)
#pragma unroll
        for (int mi = 0; mi < 2; ++mi)
          acc_c[fi][mi] = mfma16(bfr[fi], aq[mi][kk], acc_c[fi][mi]);
    }
    // Phase A: scores + per-row tile max
    float pm0 = -INFINITY, pm1 = -INFINITY;
#pragma unroll
    for (int fi = 0; fi < 4; ++fi)
#pragma unroll
      for (int mi = 0; mi < 2; ++mi){
        int row = R0 + wm*32 + mi*16 + l16;
        int c0 = C0 + wn*64 + fi*16 + quad*4;
#pragma unroll
        for (int r = 0; r < 4; ++r){
          float su = acc_u[fi][mi][r];
          float s = acc_c[fi][mi][r] * SCALE - su / (1.f + expf(-su));
          if (c0 + r > row) s = -INFINITY;
          acc_u[fi][mi][r] = s;
          if (mi) pm1 = fmaxf(pm1, s); else pm0 = fmaxf(pm0, s);
        }
      }
    pm0 = fmaxf(pm0, __shfl_xor(pm0, 16)); pm0 = fmaxf(pm0, __shfl_xor(pm0, 32));
    pm1 = fmaxf(pm1, __shfl_xor(pm1, 16)); pm1 = fmaxf(pm1, __shfl_xor(pm1, 32));
    if (quad == 0){
      wpm[wn][wm*32 + l16]      = pm0;
      wpm[wn][wm*32 + 16 + l16] = pm1;
    }
    __syncthreads();
    // Phase B: state update (wave 0)
    if (t < 64){
      float pmax = fmaxf(wpm[0][t], wpm[1][t]);
      float mo = mrun_s[t], mn = fmaxf(mo, pmax);
      alpha_s[t] = expf(mo - mn);
      mrun_s[t] = mn;
    }
    __syncthreads();
    // Phase C: probs = exp(s - m), row sums, write probs bf16 to LDS
    float mr0 = mrun_s[wm*32 + l16], mr1 = mrun_s[wm*32 + 16 + l16];
    float ps0 = 0.f, ps1 = 0.f;
#pragma unroll
    for (int fi = 0; fi < 4; ++fi)
#pragma unroll
      for (int mi = 0; mi < 2; ++mi){
        ushort4 o;
#pragma unroll
        for (int r = 0; r < 4; ++r){
          float p = expf(acc_u[fi][mi][r] - (mi ? mr1 : mr0));
          if (mi) ps1 += p; else ps0 += p;
          ((unsigned short*)&o)[r] = f2bf(p);
        }
        *(ushort4*)(probs + (wm*32 + mi*16 + l16) * 136 + wn*64 + fi*16 + quad*4) = o;
      }
    ps0 += __shfl_xor(ps0, 16); ps0 += __shfl_xor(ps0, 32);
    ps1 += __shfl_xor(ps1, 16); ps1 += __shfl_xor(ps1, 32);
    if (quad == 0){
      wps[wn][wm*32 + l16]      = ps0;
      wps[wn][wm*32 + 16 + l16] = ps1;
    }
    __syncthreads();
    // Phase D: s update (wave 0), O rescale + PV accumulate (all waves)
    if (t < 64) srun_s[t] = srun_s[t] * alpha_s[t] + wps[0][t] + wps[1][t];
    float al[4];
#pragma unroll
    for (int r = 0; r < 4; ++r) al[r] = alpha_s[16*w + quad*4 + r];
#pragma unroll
    for (int fi = 0; fi < 4; ++fi)
#pragma unroll
      for (int r = 0; r < 4; ++r) acc_o[fi][r] *= al[r];
    const unsigned short* pr = probs + (16*w + l16) * 136 + quad * 8;
#pragma unroll
    for (int k0 = 0; k0 < 4; ++k0){
      bf16x8 a = *(const bf16x8*)(pr + k0*32);
#pragma unroll
      for (int fi = 0; fi < 4; ++fi){
        bf16x8 b = ld8(Vt + (size_t)(fi*16 + l16) * 1024 + C0 + k0*32 + quad*8);
        acc_o[fi] = mfma16(a, b, acc_o[fi]);
      }
    }
    // next tile's staging barriers separate phase D from reuse of LDS state
  }
  __syncthreads();
  // epilogue: stage O through LDS (probs region overlaid as f32 [64][64])
  float* red = (float*)probs;
#pragma unroll
  for (int fi = 0; fi < 4; ++fi)
#pragma unroll
    for (int r = 0; r < 4; ++r)
      red[(16*w + quad*4 + r) * 64 + fi*16 + l16] = acc_o[fi][r];
  __syncthreads();
  int b_ = bh >> 3, h_ = bh & 7;
  if (G == 1){
#pragma unroll
    for (int pass = 0; pass < 4; ++pass){
      int e = pass * 1024 + t * 4;
      int row = e >> 6, col = e & 63;
      float inv = 1.f / srun_s[row];
      float4 v = *(const float4*)(red + e);
      ushort4 o;
      o.x = f2bf(v.x * inv); o.y = f2bf(v.y * inv);
      o.z = f2bf(v.z * inv); o.w = f2bf(v.w * inv);
      *(ushort4*)(O2 + (size_t)(b_*1024 + R0 + row) * 512 + h_*64 + col) = o;
    }
  } else {
    int slot = bh * 64 + rb * 4 + g;
#pragma unroll
    for (int pass = 0; pass < 4; ++pass){
      int e = pass * 1024 + t * 4;
      *(float4*)(Opart + (size_t)slot * 4096 + e) = *(const float4*)(red + e);
    }
    if (t < 64){
      MS[(size_t)slot * 128 + t*2]     = mrun_s[t];
      MS[(size_t)slot * 128 + t*2 + 1] = srun_s[t];
    }
  }
}

// ---------------- K4: combine split partials -> O2 (bands rb>=4) ------------
__global__ __launch_bounds__(256) void k_comb(
    const float* __restrict__ Opart, const float* __restrict__ MS,
    unsigned short* __restrict__ O2){
  int t = threadIdx.x;
  int bh = blockIdx.x & 15, rb = 4 + (blockIdx.x >> 4);
  int T = (rb >> 1) + 1, G = (T + 1) >> 1;
  int r = t >> 2, cb = (t & 3) * 16;
  int base = bh * 64 + rb * 4;
  float m = -INFINITY;
#pragma unroll
  for (int g2 = 0; g2 < 4; ++g2)
    if (g2 < G) m = fmaxf(m, MS[(size_t)(base + g2) * 128 + r*2]);
  float wg0 = 0.f, wg1 = 0.f, wg2 = 0.f, wg3 = 0.f, den = 0.f;
  if (0 < G){ wg0 = expf(MS[(size_t)(base+0)*128 + r*2] - m); den += MS[(size_t)(base+0)*128 + r*2 + 1] * wg0; }
  if (1 < G){ wg1 = expf(MS[(size_t)(base+1)*128 + r*2] - m); den += MS[(size_t)(base+1)*128 + r*2 + 1] * wg1; }
  if (2 < G){ wg2 = expf(MS[(size_t)(base+2)*128 + r*2] - m); den += MS[(size_t)(base+2)*128 + r*2 + 1] * wg2; }
  if (3 < G){ wg3 = expf(MS[(size_t)(base+3)*128 + r*2] - m); den += MS[(size_t)(base+3)*128 + r*2 + 1] * wg3; }
  float inv = 1.f / den;
  int b_ = bh >> 3, h_ = bh & 7;
#pragma unroll
  for (int c4 = 0; c4 < 4; ++c4){
    float ax = 0.f, ay = 0.f, az = 0.f, aw = 0.f;
#pragma unroll
    for (int g2 = 0; g2 < 4; ++g2){
      if (g2 < G){
        float wgv = (g2 == 0) ? wg0 : (g2 == 1) ? wg1 : (g2 == 2) ? wg2 : wg3;
        float4 v = *(const float4*)(Opart + (size_t)(base + g2) * 4096 + r*64 + cb + c4*4);
        ax += v.x * wgv; ay += v.y * wgv; az += v.z * wgv; aw += v.w * wgv;
      }
    }
    ushort4 o;
    o.x = f2bf(ax * inv); o.y = f2bf(ay * inv);
    o.z = f2bf(az * inv); o.w = f2bf(aw * inv);
    *(ushort4*)(O2 + (size_t)(b_*1024 + rb*64 + r) * 512 + h_*64 + cb + c4*4) = o;
  }
}

// ---------------- K5: out(f32) = O_cat @ w_out (contiguous A reads) ---------
__global__ __launch_bounds__(256) void k_out(
    const unsigned short* __restrict__ O2, const unsigned short* __restrict__ woT,
    float* __restrict__ out){
  __shared__ float red[4][1024];
  int t = threadIdx.x, lane = t & 63, l16 = lane & 15, quad = lane >> 4, w = t >> 6;
  int mt = blockIdx.x >> 3, nt = blockIdx.x & 7;
  int m0 = mt * 16, n0 = nt * 64;
  int r_ = m0 + l16;
  f32x4 acc[4] = {};
#pragma unroll
  for (int s = 0; s < 4; ++s){
    int kk = w * 128 + s * 32 + quad * 8;
    bf16x8 a = ld8(O2 + (size_t)r_ * 512 + kk);
#pragma unroll
    for (int fi = 0; fi < 4; ++fi){
      bf16x8 b = ld8(woT + (size_t)(n0 + fi*16 + l16) * 512 + kk);
      acc[fi] = mfma16(a, b, acc[fi]);
    }
  }
#pragma unroll
  for (int fi = 0; fi < 4; ++fi)
#pragma unroll
    for (int r = 0; r < 4; ++r)
      red[w][(quad*4 + r) * 64 + fi*16 + l16] = acc[fi][r];
  __syncthreads();
  float4 a0 = ((const float4*)red[0])[t];
  float4 a1 = ((const float4*)red[1])[t];
  float4 a2 = ((const float4*)red[2])[t];
  float4 a3 = ((const float4*)red[3])[t];
  float4 o;
  o.x = a0.x + a1.x + a2.x + a3.x;
  o.y = a0.y + a1.y + a2.y + a3.y;
  o.z = a0.z + a1.z + a2.z + a3.z;
  o.w = a0.w + a1.w + a2.w + a3.w;
  int e = t * 4, row = e >> 6, col = e & 63;
  *(float4*)(out + (size_t)(m0 + row) * 512 + n0 + col) = o;
}

extern "C" void kernel_launch(void* const* d_in, const int* in_sizes, int n_in,
                              void* d_out, int out_size, void* d_ws, size_t ws_size,
                              hipStream_t stream){
  const float* x = (const float*)d_in[0];
  float* out = (float*)d_out;
  unsigned short* ws = (unsigned short*)d_ws;

  unsigned short* wT    = ws;                                   // 7*262144
  unsigned short* xb    = wT    + (size_t)7  * 262144;          // 1048576
  unsigned short* P     = xb    + (size_t)1048576;              // 96*65536
  unsigned short* vcT   = P     + (size_t)96 * 65536;           // 16*65536
  unsigned short* term1 = vcT   + (size_t)16 * 65536;           // 16*1048576
  unsigned short* sig   = term1 + (size_t)16 * 1048576;         // 16*1048576
  unsigned short* O2    = sig   + (size_t)16 * 1048576;         // 16*65536 ([2048][512])
  unsigned short* fwsp  = O2    + (size_t)16 * 65536;           // 16*1048576 (f32 partials)
  float* Opart = (float*)fwsp;                                  // 1024 slots * 4096 f32
  float* MS    = Opart + (size_t)1024 * 4096;                   // 1024 slots * 128 f32

  k_prep<<<1024, 256, 0, stream>>>(
      x,
      (const float*)d_in[1], (const float*)d_in[2], (const float*)d_in[3],
      (const float*)d_in[4], (const float*)d_in[5], (const float*)d_in[6],
      (const float*)d_in[7], xb, wT);
  k_proj<<<768, 256, 0, stream>>>(xb, wT, P);
  k_qk_vct<<<2560, 256, 0, stream>>>(P, term1, sig, vcT);
  k_flash<<<640, 256, 0, stream>>>(P, term1, sig, vcT, Opart, MS, O2);
  k_comb<<<192, 256, 0, stream>>>(Opart, MS, O2);
  k_out<<<1024, 256, 0, stream>>>(O2, wT + (size_t)6 * 262144, out);
}